// Round 13
// baseline (37.158 us; speedup 1.0000x reference)
//
#include <hip/hip_runtime.h>
#include <stdint.h>

#define B 512
#define D 128
#define HALFC 131072u
#define SUB 2
#define NSLOT (SUB * 8)   /* 2 subs x 8 waves = 16 anchor slots per row */
#define NPART (B * SUB)

__device__ __forceinline__ uint32_t rotl32(uint32_t x, uint32_t r) {
  return (x << r) | (x >> (32u - r));
}

// Exact JAX/XLA threefry2x32 (20 rounds, key-schedule injections every 4).
__device__ __forceinline__ void threefry2x32(uint32_t k0, uint32_t k1,
                                             uint32_t x0, uint32_t x1,
                                             uint32_t& y0, uint32_t& y1) {
  uint32_t k2 = k0 ^ k1 ^ 0x1BD11BDAu;
  x0 += k0; x1 += k1;
#define TF_R(r) { x0 += x1; x1 = rotl32(x1, r); x1 ^= x0; }
  TF_R(13) TF_R(15) TF_R(26) TF_R(6)
  x0 += k1; x1 += k2 + 1u;
  TF_R(17) TF_R(29) TF_R(16) TF_R(24)
  x0 += k2; x1 += k0 + 2u;
  TF_R(13) TF_R(15) TF_R(26) TF_R(6)
  x0 += k0; x1 += k1 + 3u;
  TF_R(17) TF_R(29) TF_R(16) TF_R(24)
  x0 += k1; x1 += k2 + 4u;
  TF_R(13) TF_R(15) TF_R(26) TF_R(6)
  x0 += k2; x1 += k0 + 5u;
#undef TF_R
  y0 = x0; y1 = x1;
}

// N independent threefry chains, fully unrolled in registers (N compile-time
// => all array indices constant, no scratch). In-place: results in x0/x1.
template <int N>
__device__ __forceinline__ void tf_multi(uint32_t k0, uint32_t k1,
                                         uint32_t (&x0)[N], uint32_t (&x1)[N]) {
  uint32_t k2 = k0 ^ k1 ^ 0x1BD11BDAu;
#pragma unroll
  for (int q = 0; q < N; ++q) { x0[q] += k0; x1[q] += k1; }
#define TFM_R(r) \
  _Pragma("unroll") for (int q = 0; q < N; ++q) { \
    x0[q] += x1[q]; x1[q] = rotl32(x1[q], r); x1[q] ^= x0[q]; }
#define TFM_INJ(a, b, c) \
  _Pragma("unroll") for (int q = 0; q < N; ++q) { x0[q] += a; x1[q] += b + c; }
  TFM_R(13) TFM_R(15) TFM_R(26) TFM_R(6)
  TFM_INJ(k1, k2, 1u)
  TFM_R(17) TFM_R(29) TFM_R(16) TFM_R(24)
  TFM_INJ(k2, k0, 2u)
  TFM_R(13) TFM_R(15) TFM_R(26) TFM_R(6)
  TFM_INJ(k0, k1, 3u)
  TFM_R(17) TFM_R(29) TFM_R(16) TFM_R(24)
  TFM_INJ(k1, k2, 4u)
  TFM_R(13) TFM_R(15) TFM_R(26) TFM_R(6)
  TFM_INJ(k2, k0, 5u)
#undef TFM_R
#undef TFM_INJ
}

// 64-lane max-reduce via DPP (rocPRIM pattern): row_shr 1/2/4/8 then
// row_bcast 15/31; identity-0 fill (keys are nonnegative); result in lane 63.
__device__ __forceinline__ uint32_t dpp_max_all(uint32_t x) {
  uint32_t t;
#define DPP_STEP(ctrl) \
  t = (uint32_t)__builtin_amdgcn_update_dpp(0, (int)x, ctrl, 0xf, 0xf, true); \
  x = (t > x) ? t : x;
  DPP_STEP(0x111)  // row_shr:1
  DPP_STEP(0x112)  // row_shr:2
  DPP_STEP(0x114)  // row_shr:4
  DPP_STEP(0x118)  // row_shr:8
  DPP_STEP(0x142)  // row_bcast:15
  DPP_STEP(0x143)  // row_bcast:31
#undef DPP_STEP
  return (uint32_t)__builtin_amdgcn_readlane((int)x, 63);
}

// K1: tiled dist "GEMM". Block (ti,tj) computes a 32x32 tile of dist from two
// coalesced-staged 32x128 LDS panels (fused sq). Block 0 also computes the
// 512 anchor keys.
__global__ __launch_bounds__(256) void dist_kernel(
    const float* __restrict__ emb, float* __restrict__ dist,
    uint32_t* __restrict__ keys0, uint32_t* __restrict__ keys1) {
  __shared__ float As[32][132];  // pad 132: bank = (4r + k) % 32, conflict-free
  __shared__ float Bs[32][132];
  __shared__ float sqa[32], sqb[32];
  int bid = blockIdx.x;
  int ti = bid >> 4, tj = bid & 15;
  int t = threadIdx.x;

  // coalesced stage: 32 rows x 128 floats = 1024 float4 per panel
  const float4* ga = reinterpret_cast<const float4*>(emb + (size_t)ti * 32 * D);
  const float4* gb = reinterpret_cast<const float4*>(emb + (size_t)tj * 32 * D);
  #pragma unroll
  for (int k = 0; k < 4; ++k) {
    int idx = t + k * 256;   // float4 index 0..1023
    int r = idx >> 5;        // 32 float4 per row
    int c4 = idx & 31;
    *reinterpret_cast<float4*>(&As[r][c4 * 4]) = ga[idx];
    *reinterpret_cast<float4*>(&Bs[r][c4 * 4]) = gb[idx];
  }
  __syncthreads();

  // fused sq: 64 rows (32 A + 32 B), 4 threads/row of 32 floats each
  {
    int row = t >> 2, seg = t & 3;
    const float* src = (row < 32) ? &As[row][seg * 32] : &Bs[row - 32][seg * 32];
    float s = 0.f;
    #pragma unroll
    for (int m = 0; m < 32; ++m) { float v = src[m]; s += v * v; }
    s += __shfl_xor(s, 1);
    s += __shfl_xor(s, 2);
    if (seg == 0) { if (row < 32) sqa[row] = s; else sqb[row - 32] = s; }
  }

  // dots: thread (r = t>>3, g = t&7) computes cols c = g + 8j, j=0..3
  int r = t >> 3, g = t & 7;
  const float4* A4 = reinterpret_cast<const float4*>(&As[r][0]);
  const float4* B0 = reinterpret_cast<const float4*>(&Bs[g][0]);
  const float4* B1 = reinterpret_cast<const float4*>(&Bs[g + 8][0]);
  const float4* B2 = reinterpret_cast<const float4*>(&Bs[g + 16][0]);
  const float4* B3 = reinterpret_cast<const float4*>(&Bs[g + 24][0]);
  float acc0 = 0.f, acc1 = 0.f, acc2 = 0.f, acc3 = 0.f;
  #pragma unroll 8
  for (int k4 = 0; k4 < 32; ++k4) {
    float4 a = A4[k4];
    float4 b0 = B0[k4], b1 = B1[k4], b2 = B2[k4], b3 = B3[k4];
    acc0 += a.x * b0.x + a.y * b0.y + a.z * b0.z + a.w * b0.w;
    acc1 += a.x * b1.x + a.y * b1.y + a.z * b1.z + a.w * b1.w;
    acc2 += a.x * b2.x + a.y * b2.y + a.z * b2.z + a.w * b2.w;
    acc3 += a.x * b3.x + a.y * b3.y + a.z * b3.z + a.w * b3.w;
  }
  __syncthreads();  // sqa/sqb ready
  float sa = sqa[r];
  float* drow = dist + (size_t)(ti * 32 + r) * B + tj * 32;
  drow[g]      = sqrtf(fmaxf(sa + sqb[g]      - 2.f * acc0, 0.f));
  drow[g + 8]  = sqrtf(fmaxf(sa + sqb[g + 8]  - 2.f * acc1, 0.f));
  drow[g + 16] = sqrtf(fmaxf(sa + sqb[g + 16] - 2.f * acc2, 0.f));
  drow[g + 24] = sqrtf(fmaxf(sa + sqb[g + 24] - 2.f * acc3, 0.f));

  // block 0 tail: anchor keys
  // keys[p] from split(key(42), 512): out[q] = q<512 ? y0(q,q+512) : y1(q-512,q)
  if (bid == 0) {
    #pragma unroll
    for (int pp = 0; pp < 2; ++pp) {
      int p = t + pp * 256;
      uint32_t i0 = 2u * (uint32_t)p, i1 = i0 + 1u;
      uint32_t a0, a1, b0, b1;
      if (p < 256) {
        threefry2x32(0u, 42u, i0, i0 + 512u, a0, a1);
        threefry2x32(0u, 42u, i1, i1 + 512u, b0, b1);
        keys0[p] = a0; keys1[p] = b0;
      } else {
        threefry2x32(0u, 42u, i0 - 512u, i0, a0, a1);
        threefry2x32(0u, 42u, i1 - 512u, i1, b0, b1);
        keys0[p] = a1; keys1[p] = b1;
      }
    }
  }
}

// K2 (row-major): 512-thread blocks (8 waves), SUB=2 per row, pinned at
// 8 waves/SIMD via __launch_bounds__(512,8) (VGPR <= 64). Drain capped at
// 2 chains/call to bound live registers; anchor loop not unrolled.
__global__ __launch_bounds__(512, 8) void triplet_kernel(
    const float* __restrict__ dist, const int* __restrict__ labels,
    const uint32_t* __restrict__ keys0, const uint32_t* __restrict__ keys1,
    double* __restrict__ partials, int* __restrict__ pcnt) {
  __shared__ float drow[B];
  __shared__ unsigned short slab[B];
  __shared__ uint2 skeys[B];
  __shared__ unsigned short list_sh[B];
  __shared__ unsigned short cand[8][B];
  __shared__ int nlist_sh;
  __shared__ double lsum[8];
  __shared__ unsigned int lcnt[8];

  int bid = blockIdx.x;
  int i = bid >> 1;  // SUB = 2
  int sub = bid & 1;
  int t = threadIdx.x;
  slab[t] = (unsigned short)labels[t];
  drow[t] = dist[(size_t)i * B + t];
  skeys[t] = make_uint2(keys0[t], keys1[t]);
  __syncthreads();

  int wave = t >> 6, lane = t & 63;
  unsigned long long lmask_lt = (1ull << lane) - 1ull;
  unsigned short lab_i = slab[i];

  // wave 0: ascending list of same-label anchors p (includes i; sentineled)
  if (wave == 0) {
    int n = 0;
    #pragma unroll
    for (int c = 0; c < 8; ++c) {
      int r = c * 64 + lane;
      bool v = (slab[r] == lab_i);
      unsigned long long mk = __ballot(v);
      if (v) list_sh[n + __popcll(mk & lmask_lt)] = (unsigned short)r;
      n += __popcll(mk);
    }
    if (lane == 0) nlist_sh = (n == B) ? 0 : n;  // n==B -> no negatives
  }

  // row-invariant per-lane data: sentinel-masked distances + hard argmin.
  float dd8m[8];
  unsigned long long hkey = ~0ull;
  #pragma unroll
  for (int jc = 0; jc < 8; ++jc) {
    int j = jc * 64 + lane;
    float dv = drow[j];
    bool neg = (slab[j] != lab_i);
    dd8m[jc] = neg ? dv : -3.0e38f;
    if (neg) {
      unsigned long long k =
          (((unsigned long long)__float_as_uint(dv)) << 9) | (unsigned)j;
      if (k < hkey) hkey = k;
    }
  }
  #pragma unroll
  for (int off = 32; off; off >>= 1) {
    unsigned long long o = __shfl_xor(hkey, off);
    if (o < hkey) hkey = o;
  }
  int hard = (int)(hkey & 0x1FFu);  // valid whenever any negative exists
  uint32_t rowbase = (uint32_t)((i & 255) * B);
  bool take_hi = (i >= 256);
  __syncthreads();  // list_sh / nlist_sh ready

  int nlist = nlist_sh;
  unsigned short* wcand = cand[wave];
  double wsum = 0.0;
  unsigned int wcnt = 0;

#define LOAD_ANCHOR(KK, KP, PD) { \
    int p_ = list_sh[KK]; \
    p_ = __builtin_amdgcn_readfirstlane(p_); \
    KP = skeys[p_]; \
    PD = (p_ == i) ? -2.0f : drow[p_]; /* sentinel: window (-2,-1) empty */ }

// One drain step of NCH chains starting at candidate index c0 (+64 per chain).
#define DRAIN(NCH) { \
    uint32_t xs0[NCH], xs1[NCH], js[NCH]; \
    _Pragma("unroll") for (int q = 0; q < NCH; ++q) { \
      int c_ = c0 + q * 64; \
      uint32_t j_ = wcand[(c_ < nc) ? c_ : 0]; \
      js[q] = j_; \
      xs0[q] = rowbase + j_; \
      xs1[q] = rowbase + j_ + HALFC; \
    } \
    tf_multi<NCH>(kp.x, kp.y, xs0, xs1); \
    _Pragma("unroll") for (int q = 0; q < NCH; ++q) { \
      int c_ = c0 + q * 64; \
      uint32_t kk = ((take_hi ? xs1[q] : xs0[q]) & 0xFFFFFE00u) | \
                    (511u - js[q]); \
      if (c_ < nc && kk > best) best = kk; \
    } }

  int k = sub * 8 + wave;
  uint2 kpN; float pdN;
  if (k < nlist) LOAD_ANCHOR(k, kpN, pdN);

  #pragma unroll 1
  while (k < nlist) {
    uint2 kp = kpN;
    float pos_d = pdN;
    int kn = k + NSLOT;
    if (kn < nlist) LOAD_ANCHOR(kn, kpN, pdN);  // prefetch next anchor
    float hiv = pos_d + 1.0f;  // margin = 1.0

    int nc = 0;
    #pragma unroll
    for (int jc = 0; jc < 8; ++jc) {
      float dd = dd8m[jc];
      bool m = (dd > pos_d) && (dd < hiv);  // sentinel folds the label test
      unsigned long long mk = __ballot(m);
      if (m) wcand[nc + __popcll(mk & lmask_lt)] =
          (unsigned short)(jc * 64 + lane);
      nc += __popcll(mk);
    }

    float tl;
    if (nc > 0) {
      // packed key: (bits23 << 9) | (511 - j); max -> max bits, tie -> min j
      uint32_t best = 0u;
      int nch = (nc + 63) >> 6;  // chains needed (wave-uniform)
      int c0 = lane;
      #pragma unroll 1
      while (nch > 2) { DRAIN(2); c0 += 128; nch -= 2; }
      if (nch == 2) { DRAIN(2); } else { DRAIN(1); }
      best = dpp_max_all(best);
      int idx = 511 - (int)(best & 0x1FFu);
      tl = pos_d - drow[idx] + 1.0f;
    } else {
      tl = pos_d - drow[hard] + 1.0f;  // sentinel pos_d=-2 -> tl<0, dropped
    }
    if (tl > 0.f) { wsum += (double)tl; wcnt++; }
    k = kn;
  }
#undef LOAD_ANCHOR
#undef DRAIN

  if (lane == 0) { lsum[wave] = wsum; lcnt[wave] = wcnt; }
  __syncthreads();
  if (t == 0) {
    double s = 0.0;
    unsigned int c = 0;
    #pragma unroll
    for (int w = 0; w < 8; ++w) { s += lsum[w]; c += lcnt[w]; }
    partials[bid] = s;
    pcnt[bid] = (int)c;
  }
}

// K3: deterministic fixed-order reduction of the 1024 block partials.
__global__ __launch_bounds__(256) void finalize_kernel(
    const double* __restrict__ partials, const int* __restrict__ pcnt,
    float* __restrict__ out) {
  __shared__ double ss[256];
  __shared__ int sc[256];
  int t = threadIdx.x;
  double s = 0.0;
  int c = 0;
  for (int k = t; k < NPART; k += 256) { s += partials[k]; c += pcnt[k]; }
  ss[t] = s; sc[t] = c;
  __syncthreads();
  for (int st = 128; st; st >>= 1) {
    if (t < st) { ss[t] += ss[t + st]; sc[t] += sc[t + st]; }
    __syncthreads();
  }
  if (t == 0) out[0] = sc[0] ? (float)(ss[0] / (double)sc[0]) : 0.0f;
}

extern "C" void kernel_launch(void* const* d_in, const int* in_sizes, int n_in,
                              void* d_out, int out_size, void* d_ws, size_t ws_size,
                              hipStream_t stream) {
  const float* emb = (const float*)d_in[0];
  const int* labels = (const int*)d_in[1];
  float* out = (float*)d_out;
  char* ws = (char*)d_ws;

  float* dist = (float*)ws;                            // 1 MB
  uint32_t* keys0 = (uint32_t*)(ws + 1048576);         // 2 KB
  uint32_t* keys1 = (uint32_t*)(ws + 1048576 + 2048);  // 2 KB
  double* partials = (double*)(ws + 1048576 + 4096);   // 8 KB
  int* pcnt = (int*)(ws + 1048576 + 4096 + 8192);      // 4 KB

  dist_kernel<<<256, 256, 0, stream>>>(emb, dist, keys0, keys1);
  triplet_kernel<<<B * SUB, 512, 0, stream>>>(dist, labels, keys0, keys1,
                                              partials, pcnt);
  finalize_kernel<<<1, 256, 0, stream>>>(partials, pcnt, out);
}

// Round 14
// 36.414 us; speedup vs baseline: 1.0204x; 1.0204x over previous
//
#include <hip/hip_runtime.h>
#include <stdint.h>

#define B 512
#define D 128
#define HALFC 131072u
#define SUB 2
#define NSLOT (SUB * 8)   /* 2 subs x 8 waves = 16 anchor slots per row */
#define NPART (B * SUB)

__device__ __forceinline__ uint32_t rotl32(uint32_t x, uint32_t r) {
  return (x << r) | (x >> (32u - r));
}

// Exact JAX/XLA threefry2x32 (20 rounds, key-schedule injections every 4).
__device__ __forceinline__ void threefry2x32(uint32_t k0, uint32_t k1,
                                             uint32_t x0, uint32_t x1,
                                             uint32_t& y0, uint32_t& y1) {
  uint32_t k2 = k0 ^ k1 ^ 0x1BD11BDAu;
  x0 += k0; x1 += k1;
#define TF_R(r) { x0 += x1; x1 = rotl32(x1, r); x1 ^= x0; }
  TF_R(13) TF_R(15) TF_R(26) TF_R(6)
  x0 += k1; x1 += k2 + 1u;
  TF_R(17) TF_R(29) TF_R(16) TF_R(24)
  x0 += k2; x1 += k0 + 2u;
  TF_R(13) TF_R(15) TF_R(26) TF_R(6)
  x0 += k0; x1 += k1 + 3u;
  TF_R(17) TF_R(29) TF_R(16) TF_R(24)
  x0 += k1; x1 += k2 + 4u;
  TF_R(13) TF_R(15) TF_R(26) TF_R(6)
  x0 += k2; x1 += k0 + 5u;
#undef TF_R
  y0 = x0; y1 = x1;
}

// N independent threefry chains, fully unrolled in registers.
template <int N>
__device__ __forceinline__ void tf_multi(uint32_t k0, uint32_t k1,
                                         uint32_t (&x0)[N], uint32_t (&x1)[N]) {
  uint32_t k2 = k0 ^ k1 ^ 0x1BD11BDAu;
#pragma unroll
  for (int q = 0; q < N; ++q) { x0[q] += k0; x1[q] += k1; }
#define TFM_R(r) \
  _Pragma("unroll") for (int q = 0; q < N; ++q) { \
    x0[q] += x1[q]; x1[q] = rotl32(x1[q], r); x1[q] ^= x0[q]; }
#define TFM_INJ(a, b, c) \
  _Pragma("unroll") for (int q = 0; q < N; ++q) { x0[q] += a; x1[q] += b + c; }
  TFM_R(13) TFM_R(15) TFM_R(26) TFM_R(6)
  TFM_INJ(k1, k2, 1u)
  TFM_R(17) TFM_R(29) TFM_R(16) TFM_R(24)
  TFM_INJ(k2, k0, 2u)
  TFM_R(13) TFM_R(15) TFM_R(26) TFM_R(6)
  TFM_INJ(k0, k1, 3u)
  TFM_R(17) TFM_R(29) TFM_R(16) TFM_R(24)
  TFM_INJ(k1, k2, 4u)
  TFM_R(13) TFM_R(15) TFM_R(26) TFM_R(6)
  TFM_INJ(k2, k0, 5u)
#undef TFM_R
#undef TFM_INJ
}

// 64-lane max-reduce via DPP: row_shr 1/2/4/8 then row_bcast 15/31.
__device__ __forceinline__ uint32_t dpp_max_all(uint32_t x) {
  uint32_t t;
#define DPP_STEP(ctrl) \
  t = (uint32_t)__builtin_amdgcn_update_dpp(0, (int)x, ctrl, 0xf, 0xf, true); \
  x = (t > x) ? t : x;
  DPP_STEP(0x111)  // row_shr:1
  DPP_STEP(0x112)  // row_shr:2
  DPP_STEP(0x114)  // row_shr:4
  DPP_STEP(0x118)  // row_shr:8
  DPP_STEP(0x142)  // row_bcast:15
  DPP_STEP(0x143)  // row_bcast:31
#undef DPP_STEP
  return (uint32_t)__builtin_amdgcn_readlane((int)x, 63);
}

// K1: tiled dist "GEMM" (unchanged from r13). Block 0 computes anchor keys.
__global__ __launch_bounds__(256) void dist_kernel(
    const float* __restrict__ emb, float* __restrict__ dist,
    uint32_t* __restrict__ keys0, uint32_t* __restrict__ keys1) {
  __shared__ float As[32][132];
  __shared__ float Bs[32][132];
  __shared__ float sqa[32], sqb[32];
  int bid = blockIdx.x;
  int ti = bid >> 4, tj = bid & 15;
  int t = threadIdx.x;

  const float4* ga = reinterpret_cast<const float4*>(emb + (size_t)ti * 32 * D);
  const float4* gb = reinterpret_cast<const float4*>(emb + (size_t)tj * 32 * D);
  #pragma unroll
  for (int k = 0; k < 4; ++k) {
    int idx = t + k * 256;
    int r = idx >> 5;
    int c4 = idx & 31;
    *reinterpret_cast<float4*>(&As[r][c4 * 4]) = ga[idx];
    *reinterpret_cast<float4*>(&Bs[r][c4 * 4]) = gb[idx];
  }
  __syncthreads();

  {
    int row = t >> 2, seg = t & 3;
    const float* src = (row < 32) ? &As[row][seg * 32] : &Bs[row - 32][seg * 32];
    float s = 0.f;
    #pragma unroll
    for (int m = 0; m < 32; ++m) { float v = src[m]; s += v * v; }
    s += __shfl_xor(s, 1);
    s += __shfl_xor(s, 2);
    if (seg == 0) { if (row < 32) sqa[row] = s; else sqb[row - 32] = s; }
  }

  int r = t >> 3, g = t & 7;
  const float4* A4 = reinterpret_cast<const float4*>(&As[r][0]);
  const float4* B0 = reinterpret_cast<const float4*>(&Bs[g][0]);
  const float4* B1 = reinterpret_cast<const float4*>(&Bs[g + 8][0]);
  const float4* B2 = reinterpret_cast<const float4*>(&Bs[g + 16][0]);
  const float4* B3 = reinterpret_cast<const float4*>(&Bs[g + 24][0]);
  float acc0 = 0.f, acc1 = 0.f, acc2 = 0.f, acc3 = 0.f;
  #pragma unroll 8
  for (int k4 = 0; k4 < 32; ++k4) {
    float4 a = A4[k4];
    float4 b0 = B0[k4], b1 = B1[k4], b2 = B2[k4], b3 = B3[k4];
    acc0 += a.x * b0.x + a.y * b0.y + a.z * b0.z + a.w * b0.w;
    acc1 += a.x * b1.x + a.y * b1.y + a.z * b1.z + a.w * b1.w;
    acc2 += a.x * b2.x + a.y * b2.y + a.z * b2.z + a.w * b2.w;
    acc3 += a.x * b3.x + a.y * b3.y + a.z * b3.z + a.w * b3.w;
  }
  __syncthreads();
  float sa = sqa[r];
  float* drow = dist + (size_t)(ti * 32 + r) * B + tj * 32;
  drow[g]      = sqrtf(fmaxf(sa + sqb[g]      - 2.f * acc0, 0.f));
  drow[g + 8]  = sqrtf(fmaxf(sa + sqb[g + 8]  - 2.f * acc1, 0.f));
  drow[g + 16] = sqrtf(fmaxf(sa + sqb[g + 16] - 2.f * acc2, 0.f));
  drow[g + 24] = sqrtf(fmaxf(sa + sqb[g + 24] - 2.f * acc3, 0.f));

  if (bid == 0) {
    #pragma unroll
    for (int pp = 0; pp < 2; ++pp) {
      int p = t + pp * 256;
      uint32_t i0 = 2u * (uint32_t)p, i1 = i0 + 1u;
      uint32_t a0, a1, b0, b1;
      if (p < 256) {
        threefry2x32(0u, 42u, i0, i0 + 512u, a0, a1);
        threefry2x32(0u, 42u, i1, i1 + 512u, b0, b1);
        keys0[p] = a0; keys1[p] = b0;
      } else {
        threefry2x32(0u, 42u, i0 - 512u, i0, a0, a1);
        threefry2x32(0u, 42u, i1 - 512u, i1, b0, b1);
        keys0[p] = a1; keys1[p] = b1;
      }
    }
  }
}

// K2 (row-major, bucket-indexed): per block build a bucket-ordered array of
// packed keys (f32bits(d)<<9 | j) for the row's negatives (hist + shfl scan +
// scatter, once). Per anchor: candidate window = contiguous superset range
// [offs[lo_b]-hist[lo_b], offs[hi_b]); exactness via integer key compares
// (bit-equal to float compares, d >= 0). No per-anchor ballot compaction.
__global__ __launch_bounds__(512) void triplet_kernel(
    const float* __restrict__ dist, const int* __restrict__ labels,
    const uint32_t* __restrict__ keys0, const uint32_t* __restrict__ keys1,
    double* __restrict__ partials, int* __restrict__ pcnt) {
  __shared__ float drow[B];
  __shared__ unsigned short slab[B];
  __shared__ uint2 skeys[B];
  __shared__ unsigned short list_sh[B];
  __shared__ uint32_t hist[B];
  __shared__ uint32_t offs[B];     // inclusive scan of hist
  __shared__ uint32_t cur[B];      // scatter cursors
  __shared__ unsigned long long skey_arr[B];
  __shared__ uint32_t wsum32[8];
  __shared__ uint32_t wprefix[8];
  __shared__ int nlist_sh;
  __shared__ double lsum[8];
  __shared__ unsigned int lcnt[8];

  int bid = blockIdx.x;
  int i = bid >> 1;  // SUB = 2
  int sub = bid & 1;
  int t = threadIdx.x;
  slab[t] = (unsigned short)labels[t];
  drow[t] = dist[(size_t)i * B + t];
  skeys[t] = make_uint2(keys0[t], keys1[t]);
  hist[t] = 0u;
  __syncthreads();

  int wave = t >> 6, lane = t & 63;
  unsigned long long lmask_lt = (1ull << lane) - 1ull;
  unsigned short lab_i = slab[i];

  // wave 0: ascending list of same-label anchors p (includes i; sentineled)
  if (wave == 0) {
    int n = 0;
    #pragma unroll
    for (int c = 0; c < 8; ++c) {
      int r = c * 64 + lane;
      bool v = (slab[r] == lab_i);
      unsigned long long mk = __ballot(v);
      if (v) list_sh[n + __popcll(mk & lmask_lt)] = (unsigned short)r;
      n += __popcll(mk);
    }
    if (lane == 0) nlist_sh = (n == B) ? 0 : n;  // n==B -> no negatives
  }

  // per-thread bucket + histogram (bucket = clamp(floor(16*d)) — monotone)
  float dv_t = drow[t];
  bool neg_t = (slab[t] != lab_i);
  int b_t = (int)fminf(fmaxf(dv_t * 16.0f, 0.0f), 511.0f);
  if (neg_t) atomicAdd(&hist[b_t], 1u);

  // hard-negative argmin (register/shfl only), ties -> lowest j
  unsigned long long hkey = ~0ull;
  #pragma unroll
  for (int jc = 0; jc < 8; ++jc) {
    int j = jc * 64 + lane;
    float dv = drow[j];
    if (slab[j] != lab_i) {
      unsigned long long kk =
          (((unsigned long long)__float_as_uint(dv)) << 9) | (unsigned)j;
      if (kk < hkey) hkey = kk;
    }
  }
  #pragma unroll
  for (int off = 32; off; off >>= 1) {
    unsigned long long o = __shfl_xor(hkey, off);
    if (o < hkey) hkey = o;
  }
  int hard = (int)(hkey & 0x1FFu);
  __syncthreads();  // hist + list complete

  // block-wide inclusive scan of hist (wave shfl scan + tiny cross-wave fix)
  uint32_t v = hist[t];
  #pragma unroll
  for (int d = 1; d < 64; d <<= 1) {
    uint32_t u = __shfl_up(v, d);
    if (lane >= (unsigned)d) v += u;
  }
  if (lane == 63) wsum32[wave] = v;
  __syncthreads();
  if (t == 0) {
    uint32_t acc = 0;
    #pragma unroll
    for (int w = 0; w < 8; ++w) { wprefix[w] = acc; acc += wsum32[w]; }
  }
  __syncthreads();
  uint32_t inc = v + wprefix[wave];
  offs[t] = inc;
  cur[t] = inc - hist[t];
  __syncthreads();
  // scatter packed keys bucket-ordered (in-bucket order irrelevant: the
  // selection reduce is an order-independent max over unique packed keys)
  if (neg_t) {
    uint32_t pos = atomicAdd(&cur[b_t], 1u);
    skey_arr[pos] =
        (((unsigned long long)__float_as_uint(dv_t)) << 9) | (unsigned)t;
  }
  uint32_t rowbase = (uint32_t)((i & 255) * B);
  bool take_hi = (i >= 256);
  __syncthreads();  // skey_arr ready

  int nlist = nlist_sh;
  double wsum = 0.0;
  unsigned int wcnt = 0;

#define LOAD_ANCHOR(KK, KP, PD) { \
    int p_ = list_sh[KK]; \
    p_ = __builtin_amdgcn_readfirstlane(p_); \
    KP = skeys[p_]; \
    PD = (p_ == i) ? -2.0f : drow[p_]; /* sentinel: window (-2,-1) empty */ }

// One drain step of NCH chains starting at superset index c0 (+64 per chain).
#define DRAIN(NCH) { \
    uint32_t xs0[NCH], xs1[NCH], js[NCH]; bool vd[NCH]; \
    _Pragma("unroll") for (int q = 0; q < NCH; ++q) { \
      int c_ = c0 + q * 64; \
      unsigned long long kv = skey_arr[(c_ < end) ? c_ : start]; \
      vd[q] = (c_ < end) && (kv > lokey) && (kv < hikey); \
      js[q] = (uint32_t)(kv & 0x1FFu); \
      xs0[q] = rowbase + js[q]; \
      xs1[q] = rowbase + js[q] + HALFC; \
    } \
    tf_multi<NCH>(kp.x, kp.y, xs0, xs1); \
    _Pragma("unroll") for (int q = 0; q < NCH; ++q) { \
      uint32_t kk = ((take_hi ? xs1[q] : xs0[q]) & 0xFFFFFE00u) | \
                    (511u - js[q]); \
      if (vd[q] && kk > best) best = kk; \
    } }

  int k = sub * 8 + wave;
  uint2 kpN; float pdN;
  if (k < nlist) LOAD_ANCHOR(k, kpN, pdN);

  while (k < nlist) {
    uint2 kp = kpN;
    float pos_d = pdN;
    int kn = k + NSLOT;
    if (kn < nlist) LOAD_ANCHOR(kn, kpN, pdN);  // prefetch next anchor
    float hi_f = pos_d + 1.0f;  // margin = 1.0

    int lo_b = (int)fminf(fmaxf(pos_d * 16.0f, 0.0f), 511.0f);
    int hi_b = (int)fminf(fmaxf(hi_f * 16.0f, 0.0f), 511.0f);
    int start = (int)(offs[lo_b] - hist[lo_b]);
    int end = (int)offs[hi_b];
    // exact window as integer key compares (d >= 0 -> bit order = float order)
    unsigned long long lokey =
        (((unsigned long long)__float_as_uint(pos_d)) << 9) | 511u;
    unsigned long long hikey =
        ((unsigned long long)__float_as_uint(hi_f)) << 9;

    float tl;
    if (end > start) {
      // packed key: (bits23 << 9) | (511 - j); max -> max bits, tie -> min j
      uint32_t best = 0u;
      int nch = (end - start + 63) >> 6;  // wave-uniform
      int c0 = start + lane;
      while (nch > 4) { DRAIN(4); c0 += 256; nch -= 4; }
      switch (nch) {
        case 4: DRAIN(4); break;
        case 3: DRAIN(3); break;
        case 2: DRAIN(2); break;
        default: DRAIN(1); break;
      }
      best = dpp_max_all(best);
      int idx = best ? (511 - (int)(best & 0x1FFu)) : hard;
      tl = pos_d - drow[idx] + 1.0f;
    } else {
      tl = pos_d - drow[hard] + 1.0f;  // sentinel pos_d=-2 -> tl<0, dropped
    }
    if (tl > 0.f) { wsum += (double)tl; wcnt++; }
    k = kn;
  }
#undef LOAD_ANCHOR
#undef DRAIN

  if (lane == 0) { lsum[wave] = wsum; lcnt[wave] = wcnt; }
  __syncthreads();
  if (t == 0) {
    double s = 0.0;
    unsigned int c = 0;
    #pragma unroll
    for (int w = 0; w < 8; ++w) { s += lsum[w]; c += lcnt[w]; }
    partials[bid] = s;
    pcnt[bid] = (int)c;
  }
}

// K3: deterministic fixed-order reduction of the 1024 block partials.
__global__ __launch_bounds__(256) void finalize_kernel(
    const double* __restrict__ partials, const int* __restrict__ pcnt,
    float* __restrict__ out) {
  __shared__ double ss[256];
  __shared__ int sc[256];
  int t = threadIdx.x;
  double s = 0.0;
  int c = 0;
  for (int k = t; k < NPART; k += 256) { s += partials[k]; c += pcnt[k]; }
  ss[t] = s; sc[t] = c;
  __syncthreads();
  for (int st = 128; st; st >>= 1) {
    if (t < st) { ss[t] += ss[t + st]; sc[t] += sc[t + st]; }
    __syncthreads();
  }
  if (t == 0) out[0] = sc[0] ? (float)(ss[0] / (double)sc[0]) : 0.0f;
}

extern "C" void kernel_launch(void* const* d_in, const int* in_sizes, int n_in,
                              void* d_out, int out_size, void* d_ws, size_t ws_size,
                              hipStream_t stream) {
  const float* emb = (const float*)d_in[0];
  const int* labels = (const int*)d_in[1];
  float* out = (float*)d_out;
  char* ws = (char*)d_ws;

  float* dist = (float*)ws;                            // 1 MB
  uint32_t* keys0 = (uint32_t*)(ws + 1048576);         // 2 KB
  uint32_t* keys1 = (uint32_t*)(ws + 1048576 + 2048);  // 2 KB
  double* partials = (double*)(ws + 1048576 + 4096);   // 8 KB
  int* pcnt = (int*)(ws + 1048576 + 4096 + 8192);      // 4 KB

  dist_kernel<<<256, 256, 0, stream>>>(emb, dist, keys0, keys1);
  triplet_kernel<<<B * SUB, 512, 0, stream>>>(dist, labels, keys0, keys1,
                                              partials, pcnt);
  finalize_kernel<<<1, 256, 0, stream>>>(partials, pcnt, out);
}